// Round 3
// baseline (882.873 us; speedup 1.0000x reference)
//
#include <hip/hip_runtime.h>

#define BB 2
#define TT 257
#define CC 128
#define HH 8
#define DD 16
#define C2O 256
#define NIMG (BB*TT)      // 514
#define ROWS (BB*HH*TT)   // 4112
#define KTOT 2304
#define KC 36
#define NCHUNK 64         // 2304/36

static __device__ __forceinline__ float wred_max(float v) {
    #pragma unroll
    for (int off = 32; off; off >>= 1) v = fmaxf(v, __shfl_xor(v, off, 64));
    return v;
}
static __device__ __forceinline__ float wred_sum(float v) {
    #pragma unroll
    for (int off = 32; off; off >>= 1) v += __shfl_xor(v, off, 64);
    return v;
}

#define BN_INV 0.9999950000374997f

// ---------------- Kernel A1: depthwise 3x3 + BN (+cls passthrough) ----------------
__global__ void k_pre(const float* __restrict__ x,
                      const float* __restrict__ dwq, const float* __restrict__ dwk, const float* __restrict__ dwv,
                      const float* __restrict__ gq, const float* __restrict__ bq,
                      const float* __restrict__ gk, const float* __restrict__ bk,
                      const float* __restrict__ gv, const float* __restrict__ bv,
                      float* __restrict__ pre) {
    int blk = blockIdx.x;               // which*NIMG + b*TT + t
    int which = blk / NIMG;
    int it = blk - which * NIMG;
    int b = it / TT, t = it - b * TT;
    int c = threadIdx.x;                // 128
    const float* dw = (which == 0) ? dwq : (which == 1) ? dwk : dwv;
    const float* g  = (which == 0) ? gq  : (which == 1) ? gk  : gv;
    const float* bi = (which == 0) ? bq  : (which == 1) ? bk  : bv;
    float val;
    if (t == 0) {
        val = x[(b * TT) * CC + c];
    } else {
        int y = (t - 1) >> 4, xx = (t - 1) & 15;
        float s = 0.f;
        #pragma unroll
        for (int ky = 0; ky < 3; ky++) {
            int yy = y + ky - 1;
            if (yy < 0 || yy > 15) continue;
            #pragma unroll
            for (int kx = 0; kx < 3; kx++) {
                int xb = xx + kx - 1;
                if (xb < 0 || xb > 15) continue;
                s += dw[c * 9 + ky * 3 + kx] * x[(b * TT + 1 + yy * 16 + xb) * CC + c];
            }
        }
        val = s * (g[c] * BN_INV) + bi[c];
    }
    pre[(which * NIMG + it) * CC + c] = val;
}

// ---------------- Kernel A2: QKV projection ----------------
__global__ void k_proj(const float* __restrict__ pre,
                       const float* __restrict__ Wq, const float* __restrict__ Wk, const float* __restrict__ Wv,
                       float* __restrict__ qh, float* __restrict__ kv) {
    int blk = blockIdx.x;
    int which = blk / NIMG;
    int it = blk - which * NIMG;
    int b = it / TT, t = it - b * TT;
    int o = threadIdx.x;                // 128
    __shared__ float row[CC];
    row[o] = pre[(which * NIMG + it) * CC + o];
    __syncthreads();
    const float* W = (which == 0) ? Wq : (which == 1) ? Wk : Wv;
    const float* wr = W + o * CC;
    float acc = 0.f;
    #pragma unroll 8
    for (int c = 0; c < CC; c++) acc += wr[c] * row[c];
    int hh = o >> 4, dd = o & 15;
    long ridx = (long)(b * HH + hh) * TT + t;
    if (which == 0)      qh[ridx * DD + dd] = acc;
    else if (which == 1) kv[ridx * 32 + dd] = acc;
    else                 kv[ridx * 32 + 16 + dd] = acc;
}

// ---------------- Kernel B: score = [first, 0.7*softmax(2r)+0.3*(1-softmax(-2r))] ----------------
__global__ void k_score(const float* __restrict__ asg, float* __restrict__ score) {
    int wid = threadIdx.x >> 6;
    int lane = threadIdx.x & 63;
    int r = blockIdx.x * 4 + wid;
    if (r >= ROWS) return;
    const float* src = asg + (long)r * TT;
    float* dst = score + (long)r * TT;
    float e[4];
    #pragma unroll
    for (int i = 0; i < 4; i++) e[i] = src[1 + lane + 64 * i] * 2.0f;
    float mx = fmaxf(fmaxf(e[0], e[1]), fmaxf(e[2], e[3]));
    mx = wred_max(mx);
    float mn = fminf(fminf(e[0], e[1]), fminf(e[2], e[3]));
    mn = -wred_max(-mn);
    float pe[4], ne[4], ps = 0.f, ns = 0.f;
    #pragma unroll
    for (int i = 0; i < 4; i++) {
        pe[i] = expf(e[i] - mx); ps += pe[i];
        ne[i] = expf(mn - e[i]); ns += ne[i];
    }
    ps = wred_sum(ps); ns = wred_sum(ns);
    float rp = 1.f / ps, rn = 1.f / ns;
    #pragma unroll
    for (int i = 0; i < 4; i++)
        dst[1 + lane + 64 * i] = 0.7f * pe[i] * rp + 0.3f * (1.f - ne[i] * rn);
    if (lane == 0) dst[0] = src[0];
}

// ---------------- Kernel Wt: conv_w [o][k] -> [k][o] ----------------
__global__ void k_wt(const float* __restrict__ cw, float* __restrict__ wt) {
    int k = blockIdx.x;     // 2304
    int o = threadIdx.x;    // 256
    wt[k * C2O + o] = cw[o * KTOT + k];
}

// ---------------- Kernel C: fused implicit-GEMM conv (+bias+BN) -> cf layout ----------------
__launch_bounds__(256, 2)
__global__ void k_conv(const float* __restrict__ wt, const float* __restrict__ score,
                       const float* __restrict__ kv, const float* __restrict__ cb,
                       const float* __restrict__ g2, const float* __restrict__ b2,
                       float* __restrict__ cf) {
    __shared__ float s_score[8][260];
    __shared__ float s_kv[8][32];
    __shared__ float s_w[KC * C2O];   // 36 KB
    __shared__ float s_ci[KC * 64];   // 9 KB
    int n = blockIdx.x;               // b*TT + t'
    int b = n / TT, tp = n - b * TT;
    int tid = threadIdx.x;

    // stage the 8 score rows + kv rows this image needs
    for (int i = tid; i < 8 * TT; i += 256) {
        int j = i / TT, s = i - j * TT;
        int m = tp * 8 + j;
        int hh = m / TT, t = m - hh * TT;
        long row = (long)(b * HH + hh) * TT + t;
        s_score[j][s] = score[row * TT + s];
    }
    {
        int j = tid >> 5, c = tid & 31;
        int m = tp * 8 + j;
        int hh = m / TT, t = m - hh * TT;
        long row = (long)(b * HH + hh) * TT + t;
        s_kv[j][c] = kv[row * 32 + c];
    }
    __syncthreads();

    int o_t = tid & 31, p_t = tid >> 5;
    float acc[8][8];
    #pragma unroll
    for (int i = 0; i < 8; i++)
        #pragma unroll
        for (int j = 0; j < 8; j++) acc[i][j] = 0.f;

    for (int ch = 0; ch < NCHUNK; ch++) {
        int k0 = ch * KC;
        // stage W chunk (contiguous, float4)
        const float4* wsrc = (const float4*)(wt + k0 * C2O);
        float4* wdst = (float4*)s_w;
        #pragma unroll
        for (int i = 0; i < 9; i++) wdst[tid + 256 * i] = wsrc[tid + 256 * i];
        // stage ci chunk (synthesized from score*kv, zero-padded)
        #pragma unroll
        for (int i = 0; i < 9; i++) {
            int e = tid + 256 * i;            // < 2304
            int kl = e >> 6, p = e & 63;
            int k = k0 + kl;
            int c2 = k / 9;
            int r = k - c2 * 9;
            int dy = r / 3, dx = r - dy * 3;
            int yo = p >> 3, xo = p & 7;
            int y = 2 * yo - 1 + dy, x = 2 * xo - 1 + dx;
            float v = 0.f;
            if ((unsigned)y < 16u && (unsigned)x < 16u) {
                int j = y >> 1;
                int sidx = 1 + ((((y & 1) << 4) + x) << 3) + (c2 >> 5);
                v = s_score[j][sidx] * s_kv[j][c2 & 31];
            }
            s_ci[kl * 64 + p] = v;
        }
        __syncthreads();
        const float4* w4 = (const float4*)s_w;
        const float4* x4 = (const float4*)s_ci;
        #pragma unroll 4
        for (int kk = 0; kk < KC; kk++) {
            float4 w0 = w4[kk * 64 + o_t];
            float4 w1 = w4[kk * 64 + 32 + o_t];
            float4 xa = x4[kk * 16 + p_t * 2];
            float4 xb = x4[kk * 16 + p_t * 2 + 1];
            float wv[8] = {w0.x, w0.y, w0.z, w0.w, w1.x, w1.y, w1.z, w1.w};
            float xv[8] = {xa.x, xa.y, xa.z, xa.w, xb.x, xb.y, xb.z, xb.w};
            #pragma unroll
            for (int io = 0; io < 8; io++)
                #pragma unroll
                for (int jp = 0; jp < 8; jp++)
                    acc[io][jp] += wv[io] * xv[jp];
        }
        __syncthreads();
    }

    // epilogue: bias + BN, write in cf layout (B,H,T,64,32)
    #pragma unroll
    for (int io = 0; io < 8; io++) {
        int o = (io < 4) ? (o_t * 4 + io) : (128 + o_t * 4 + (io - 4));
        float bias = cb[o];
        float sc = g2[o] * BN_INV;
        float sh = b2[o];
        int hh_o = o >> 5, c = o & 31;
        long rowcf = (long)(b * HH + hh_o) * TT + tp;
        #pragma unroll
        for (int jp = 0; jp < 8; jp++) {
            int p = p_t * 8 + jp;
            int pcf = 2 * c + (p >> 5);
            int cp = p & 31;
            cf[(rowcf * 64 + pcf) * 32 + cp] = (acc[io][jp] + bias) * sc + sh;
        }
    }
}

// ---------------- Kernel D: 65-key attention + GELU ----------------
__global__ void k_attn(const float* __restrict__ qh, const float* __restrict__ kv,
                       const float* __restrict__ score, const float* __restrict__ cf,
                       float* __restrict__ out) {
    int row = blockIdx.x;               // (b*8+hh)*257+t
    int lane = threadIdx.x;             // 64
    int b = row / (HH * TT);
    int rem = row - b * (HH * TT);
    int hh = rem / TT, t = rem - hh * TT;
    __shared__ float q[16];
    __shared__ float pv[66];
    __shared__ float vv[65][16];
    if (lane < 16) q[lane] = qh[(long)row * DD + lane];
    __syncthreads();
    const float SCALE = 0.08838834764831845f;
    float d, d2 = -INFINITY;
    if (lane == 0) {
        float s0 = score[(long)row * TT];
        float a = 0.f;
        #pragma unroll
        for (int i = 0; i < 16; i++) {
            float kk = s0 * kv[(long)row * 32 + i];
            a += q[i] * kk;
            vv[0][i] = s0 * kv[(long)row * 32 + 16 + i];
        }
        d = a * SCALE;
        const float* b63 = cf + ((long)row * 64 + 63) * 32;
        a = 0.f;
        #pragma unroll
        for (int i = 0; i < 16; i++) { a += q[i] * b63[i]; vv[64][i] = b63[16 + i]; }
        d2 = a * SCALE;
    } else {
        const float* bp = cf + ((long)row * 64 + (lane - 1)) * 32;
        float a = 0.f;
        #pragma unroll
        for (int i = 0; i < 16; i++) { a += q[i] * bp[i]; vv[lane][i] = bp[16 + i]; }
        d = a * SCALE;
    }
    float mx = wred_max(fmaxf(d, d2));
    float p = expf(d - mx);
    float p2 = (lane == 0) ? expf(d2 - mx) : 0.f;
    float sum = wred_sum(p + p2);
    pv[lane] = p;
    if (lane == 0) pv[64] = p2;
    __syncthreads();
    if (lane < 16) {
        float a = 0.f;
        for (int j = 0; j < 65; j++) a += pv[j] * vv[j][lane];
        float o = a / sum;
        float g = 0.5f * o * (1.f + erff(o * 0.70710678118654752f));
        out[(long)(b * TT + t) * CC + hh * DD + lane] = g;
    }
}

extern "C" void kernel_launch(void* const* d_in, const int* in_sizes, int n_in,
                              void* d_out, int out_size, void* d_ws, size_t ws_size,
                              hipStream_t stream) {
    const float* x   = (const float*)d_in[0];
    const float* asg = (const float*)d_in[1];
    const float* dwq = (const float*)d_in[2];
    const float* dwk = (const float*)d_in[3];
    const float* dwv = (const float*)d_in[4];
    const float* gq  = (const float*)d_in[5];
    const float* bq  = (const float*)d_in[6];
    const float* gk  = (const float*)d_in[7];
    const float* bk  = (const float*)d_in[8];
    const float* gv  = (const float*)d_in[9];
    const float* bv  = (const float*)d_in[10];
    const float* Wq  = (const float*)d_in[11];
    const float* Wk  = (const float*)d_in[12];
    const float* Wv  = (const float*)d_in[13];
    const float* cw  = (const float*)d_in[14];
    const float* cb  = (const float*)d_in[15];
    const float* g2  = (const float*)d_in[16];
    const float* b2  = (const float*)d_in[17];
    float* out = (float*)d_out;

    float* ws = (float*)d_ws;
    float* qh    = ws;                    // 65792
    float* kvv   = qh + 65792;            // 131584
    float* score = kvv + 131584;          // 1056784
    float* wt    = score + 1056784;       // 589824
    float* cf    = wt + 589824;           // 8421376
    float* pre   = cf + 8421376;          // 197376   (total ~41.9 MB)

    k_pre<<<3 * NIMG, CC, 0, stream>>>(x, dwq, dwk, dwv, gq, bq, gk, bk, gv, bv, pre);
    k_proj<<<3 * NIMG, CC, 0, stream>>>(pre, Wq, Wk, Wv, qh, kvv);
    k_score<<<ROWS / 4, 256, 0, stream>>>(asg, score);
    k_wt<<<KTOT, C2O, 0, stream>>>(cw, wt);
    k_conv<<<NIMG, 256, 0, stream>>>(wt, score, kvv, cb, g2, b2, cf);
    k_attn<<<ROWS, 64, 0, stream>>>(qh, kvv, score, cf, out);
}

// Round 4
// 454.376 us; speedup vs baseline: 1.9430x; 1.9430x over previous
//
#include <hip/hip_runtime.h>

#define BB 2
#define TT 257
#define CC 128
#define HH 8
#define DD 16
#define C2O 256
#define NIMG (BB*TT)      // 514
#define ROWS (BB*HH*TT)   // 4112
#define KTOT 2304

static __device__ __forceinline__ float wred_max(float v) {
    #pragma unroll
    for (int off = 32; off; off >>= 1) v = fmaxf(v, __shfl_xor(v, off, 64));
    return v;
}
static __device__ __forceinline__ float wred_sum(float v) {
    #pragma unroll
    for (int off = 32; off; off >>= 1) v += __shfl_xor(v, off, 64);
    return v;
}

#define BN_INV 0.9999950000374997f

// ---------------- Kernel A1: depthwise 3x3 + BN (+cls passthrough) ----------------
__global__ void k_pre(const float* __restrict__ x,
                      const float* __restrict__ dwq, const float* __restrict__ dwk, const float* __restrict__ dwv,
                      const float* __restrict__ gq, const float* __restrict__ bq,
                      const float* __restrict__ gk, const float* __restrict__ bk,
                      const float* __restrict__ gv, const float* __restrict__ bv,
                      float* __restrict__ pre) {
    int blk = blockIdx.x;               // which*NIMG + b*TT + t
    int which = blk / NIMG;
    int it = blk - which * NIMG;
    int b = it / TT, t = it - b * TT;
    int c = threadIdx.x;                // 128
    const float* dw = (which == 0) ? dwq : (which == 1) ? dwk : dwv;
    const float* g  = (which == 0) ? gq  : (which == 1) ? gk  : gv;
    const float* bi = (which == 0) ? bq  : (which == 1) ? bk  : bv;
    float val;
    if (t == 0) {
        val = x[(b * TT) * CC + c];
    } else {
        int y = (t - 1) >> 4, xx = (t - 1) & 15;
        float s = 0.f;
        #pragma unroll
        for (int ky = 0; ky < 3; ky++) {
            int yy = y + ky - 1;
            if (yy < 0 || yy > 15) continue;
            #pragma unroll
            for (int kx = 0; kx < 3; kx++) {
                int xb = xx + kx - 1;
                if (xb < 0 || xb > 15) continue;
                s += dw[c * 9 + ky * 3 + kx] * x[(b * TT + 1 + yy * 16 + xb) * CC + c];
            }
        }
        val = s * (g[c] * BN_INV) + bi[c];
    }
    pre[(which * NIMG + it) * CC + c] = val;
}

// ---------------- Kernel A2: QKV projection ----------------
__global__ void k_proj(const float* __restrict__ pre,
                       const float* __restrict__ Wq, const float* __restrict__ Wk, const float* __restrict__ Wv,
                       float* __restrict__ qh, float* __restrict__ kv) {
    int blk = blockIdx.x;
    int which = blk / NIMG;
    int it = blk - which * NIMG;
    int b = it / TT, t = it - b * TT;
    int o = threadIdx.x;                // 128
    __shared__ float row[CC];
    row[o] = pre[(which * NIMG + it) * CC + o];
    __syncthreads();
    const float* W = (which == 0) ? Wq : (which == 1) ? Wk : Wv;
    const float* wr = W + o * CC;
    float acc = 0.f;
    #pragma unroll 8
    for (int c = 0; c < CC; c++) acc += wr[c] * row[c];
    int hh = o >> 4, dd = o & 15;
    long ridx = (long)(b * HH + hh) * TT + t;
    if (which == 0)      qh[ridx * DD + dd] = acc;
    else if (which == 1) kv[ridx * 32 + dd] = acc;
    else                 kv[ridx * 32 + 16 + dd] = acc;
}

// ---------------- Kernel B: score = [first, 0.7*softmax(2r)+0.3*(1-softmax(-2r))] ----------------
__global__ void k_score(const float* __restrict__ asg, float* __restrict__ score) {
    int wid = threadIdx.x >> 6;
    int lane = threadIdx.x & 63;
    int r = blockIdx.x * 4 + wid;
    if (r >= ROWS) return;
    const float* src = asg + (long)r * TT;
    float* dst = score + (long)r * TT;
    float e[4];
    #pragma unroll
    for (int i = 0; i < 4; i++) e[i] = src[1 + lane + 64 * i] * 2.0f;
    float mx = fmaxf(fmaxf(e[0], e[1]), fmaxf(e[2], e[3]));
    mx = wred_max(mx);
    float mn = fminf(fminf(e[0], e[1]), fminf(e[2], e[3]));
    mn = -wred_max(-mn);
    float pe[4], ne[4], ps = 0.f, ns = 0.f;
    #pragma unroll
    for (int i = 0; i < 4; i++) {
        pe[i] = expf(e[i] - mx); ps += pe[i];
        ne[i] = expf(mn - e[i]); ns += ne[i];
    }
    ps = wred_sum(ps); ns = wred_sum(ns);
    float rp = 1.f / ps, rn = 1.f / ns;
    #pragma unroll
    for (int i = 0; i < 4; i++)
        dst[1 + lane + 64 * i] = 0.7f * pe[i] * rp + 0.3f * (1.f - ne[i] * rn);
    if (lane == 0) dst[0] = src[0];
}

// ---------------- Kernel W2: conv_w [o][c2][d] -> wt2 [o][jp][d][v]  (c2 = 32*jp + v) ----------------
__global__ void k_w2(const float* __restrict__ cw, float* __restrict__ wt2) {
    int o = blockIdx.x;     // 256
    int t = threadIdx.x;    // 256
    for (int i = t; i < KTOT; i += 256) {
        int jp = i / 288;
        int r = i - jp * 288;
        int d = r >> 5, v = r & 31;
        wt2[o * KTOT + i] = cw[o * KTOT + (jp * 32 + v) * 9 + d];
    }
}

// ---------------- Kernel C: factorized conv (rank-1 ci = S x KV) ----------------
// Stage 1: P[d][j][jp][o_l] = sum_v W[o][32jp+v][d] * KV[j][v]     (K=32)
// Stage 2: co[o][p] = sum_{d,jp} S[j(p,d)][8*(16*ypar+x)+jp] * P[d][j][jp][o_l]  (K<=72)
__launch_bounds__(256, 3)
__global__ void k_fconv(const float* __restrict__ wt2, const float* __restrict__ score,
                        const float* __restrict__ kv, const float* __restrict__ cb,
                        const float* __restrict__ g2, const float* __restrict__ b2,
                        float* __restrict__ cf) {
    __shared__ float s_S[8][256];          // score rows, cols 1..256
    __shared__ float s_kv[8][32];
    __shared__ float s_P[9][8][8][16];     // [d][j][jp][o_l]  36 KB
    int bid = blockIdx.x;
    int oc  = bid / NIMG;                  // o-chunk 0..15
    int img = bid - oc * NIMG;             // b*TT + tp
    int b = img / TT, tp = img - b * TT;
    int tid = threadIdx.x;

    // stage kv rows + score rows (cols 1..256) for this image
    {
        int j = tid >> 5, c = tid & 31;
        int m = tp * 8 + j;
        int hh = m / TT, t = m - hh * TT;
        long row = (long)(b * HH + hh) * TT + t;
        s_kv[j][c] = kv[row * 32 + c];
    }
    #pragma unroll
    for (int it = 0; it < 8; it++) {
        int i = tid + 256 * it;            // 0..2047
        int j = i >> 8, s = i & 255;
        int m = tp * 8 + j;
        int hh = m / TT, t = m - hh * TT;
        long row = (long)(b * HH + hh) * TT + t;
        s_S[j][s] = score[row * TT + 1 + s];
    }
    __syncthreads();

    // ---- stage 1 ----
    {
        int o_l = tid >> 4;                // 0..15
        int jp  = tid & 7;                 // 0..7
        int jh  = (tid >> 3) & 1;          // j-half
        const float* gw = wt2 + (((oc << 4) + o_l) * KTOT + jp * 288);
        for (int d = 0; d < 9; d++) {
            float4 wv[8];
            const float4* w4 = (const float4*)(gw + (d << 5));
            #pragma unroll
            for (int u = 0; u < 8; u++) wv[u] = w4[u];
            #pragma unroll
            for (int jj = 0; jj < 4; jj++) {
                const float4* kv4 = (const float4*)(&s_kv[(jh << 2) + jj][0]);
                float a = 0.f;
                #pragma unroll
                for (int u = 0; u < 8; u++) {
                    float4 kk = kv4[u];
                    a += wv[u].x * kk.x + wv[u].y * kk.y + wv[u].z * kk.z + wv[u].w * kk.w;
                }
                s_P[d][(jh << 2) + jj][jp][o_l] = a;
            }
        }
    }
    __syncthreads();

    // ---- stage 2 ----
    int p  = tid >> 2;                     // 0..63
    int og = (tid & 3) << 2;               // o_l base: 0,4,8,12
    int yo = p >> 3, xo = p & 7;
    float acc[4] = {0.f, 0.f, 0.f, 0.f};
    for (int dy = 0; dy < 3; dy++) {
        int y = 2 * yo - 1 + dy;
        if (y < 0) continue;               // top pad (yo=0, dy=0); y<=15 always
        int j = y >> 1, ypar = y & 1;
        #pragma unroll
        for (int dx = 0; dx < 3; dx++) {
            int x = 2 * xo - 1 + dx;
            if (x < 0) continue;           // left pad (xo=0, dx=0); x<=15 always
            int d = dy * 3 + dx;
            const float*  sp = &s_S[j][(ypar * 16 + x) << 3];
            const float4* pp = (const float4*)(&s_P[d][j][0][og]);
            #pragma unroll
            for (int jp = 0; jp < 8; jp++) {
                float s = sp[jp];
                float4 pv = pp[jp * 4];    // stride between jp = 16 floats
                acc[0] += s * pv.x; acc[1] += s * pv.y;
                acc[2] += s * pv.z; acc[3] += s * pv.w;
            }
        }
    }

    // epilogue: bias + BN -> cf layout (B,H,T,64,32)
    int pcf_hi = p >> 5, cp = p & 31;
    #pragma unroll
    for (int i = 0; i < 4; i++) {
        int o = (oc << 4) + og + i;
        int hh_o = o >> 5, c = o & 31;
        long rowcf = (long)(b * HH + hh_o) * TT + tp;
        int pcf = 2 * c + pcf_hi;
        cf[(rowcf * 64 + pcf) * 32 + cp] = (acc[i] + cb[o]) * (g2[o] * BN_INV) + b2[o];
    }
}

// ---------------- Kernel D: 65-key attention + GELU ----------------
__global__ void k_attn(const float* __restrict__ qh, const float* __restrict__ kv,
                       const float* __restrict__ score, const float* __restrict__ cf,
                       float* __restrict__ out) {
    int row = blockIdx.x;               // (b*8+hh)*257+t
    int lane = threadIdx.x;             // 64
    int b = row / (HH * TT);
    int rem = row - b * (HH * TT);
    int hh = rem / TT, t = rem - hh * TT;
    __shared__ float q[16];
    __shared__ float pv[66];
    __shared__ float vv[65][16];
    if (lane < 16) q[lane] = qh[(long)row * DD + lane];
    __syncthreads();
    const float SCALE = 0.08838834764831845f;
    float d, d2 = -INFINITY;
    if (lane == 0) {
        float s0 = score[(long)row * TT];
        float a = 0.f;
        #pragma unroll
        for (int i = 0; i < 16; i++) {
            float kk = s0 * kv[(long)row * 32 + i];
            a += q[i] * kk;
            vv[0][i] = s0 * kv[(long)row * 32 + 16 + i];
        }
        d = a * SCALE;
        const float* b63 = cf + ((long)row * 64 + 63) * 32;
        a = 0.f;
        #pragma unroll
        for (int i = 0; i < 16; i++) { a += q[i] * b63[i]; vv[64][i] = b63[16 + i]; }
        d2 = a * SCALE;
    } else {
        const float* bp = cf + ((long)row * 64 + (lane - 1)) * 32;
        float a = 0.f;
        #pragma unroll
        for (int i = 0; i < 16; i++) { a += q[i] * bp[i]; vv[lane][i] = bp[16 + i]; }
        d = a * SCALE;
    }
    float mx = wred_max(fmaxf(d, d2));
    float p = expf(d - mx);
    float p2 = (lane == 0) ? expf(d2 - mx) : 0.f;
    float sum = wred_sum(p + p2);
    pv[lane] = p;
    if (lane == 0) pv[64] = p2;
    __syncthreads();
    if (lane < 16) {
        float a = 0.f;
        for (int j = 0; j < 65; j++) a += pv[j] * vv[j][lane];
        float o = a / sum;
        float g = 0.5f * o * (1.f + erff(o * 0.70710678118654752f));
        out[(long)(b * TT + t) * CC + hh * DD + lane] = g;
    }
}

extern "C" void kernel_launch(void* const* d_in, const int* in_sizes, int n_in,
                              void* d_out, int out_size, void* d_ws, size_t ws_size,
                              hipStream_t stream) {
    const float* x   = (const float*)d_in[0];
    const float* asg = (const float*)d_in[1];
    const float* dwq = (const float*)d_in[2];
    const float* dwk = (const float*)d_in[3];
    const float* dwv = (const float*)d_in[4];
    const float* gq  = (const float*)d_in[5];
    const float* bq  = (const float*)d_in[6];
    const float* gk  = (const float*)d_in[7];
    const float* bk  = (const float*)d_in[8];
    const float* gv  = (const float*)d_in[9];
    const float* bv  = (const float*)d_in[10];
    const float* Wq  = (const float*)d_in[11];
    const float* Wk  = (const float*)d_in[12];
    const float* Wv  = (const float*)d_in[13];
    const float* cw  = (const float*)d_in[14];
    const float* cb  = (const float*)d_in[15];
    const float* g2  = (const float*)d_in[16];
    const float* b2  = (const float*)d_in[17];
    float* out = (float*)d_out;

    float* ws = (float*)d_ws;
    float* qh    = ws;                    // 65792
    float* kvv   = qh + 65792;            // 131584
    float* score = kvv + 131584;          // 1056784
    float* wt2   = score + 1056784;       // 589824
    float* cf    = wt2 + 589824;          // 8421376
    float* pre   = cf + 8421376;          // 197376   (total ~41.9 MB)

    k_pre<<<3 * NIMG, CC, 0, stream>>>(x, dwq, dwk, dwv, gq, bq, gk, bk, gv, bv, pre);
    k_proj<<<3 * NIMG, CC, 0, stream>>>(pre, Wq, Wk, Wv, qh, kvv);
    k_score<<<ROWS / 4, 256, 0, stream>>>(asg, score);
    k_w2<<<C2O, 256, 0, stream>>>(cw, wt2);
    k_fconv<<<16 * NIMG, 256, 0, stream>>>(wt2, score, kvv, cb, g2, b2, cf);
    k_attn<<<ROWS, 64, 0, stream>>>(qh, kvv, score, cf, out);
}

// Round 5
// 410.987 us; speedup vs baseline: 2.1482x; 1.1056x over previous
//
#include <hip/hip_runtime.h>

#define BB 2
#define TT 257
#define CC 128
#define HH 8
#define DD 16
#define C2O 256
#define NIMG (BB*TT)      // 514
#define ROWS (BB*HH*TT)   // 4112
#define KTOT 2304

static __device__ __forceinline__ float wred_max(float v) {
    #pragma unroll
    for (int off = 32; off; off >>= 1) v = fmaxf(v, __shfl_xor(v, off, 64));
    return v;
}
static __device__ __forceinline__ float wred_sum(float v) {
    #pragma unroll
    for (int off = 32; off; off >>= 1) v += __shfl_xor(v, off, 64);
    return v;
}

#define BN_INV 0.9999950000374997f

// ---------------- Kernel A1: depthwise 3x3 + BN (+cls passthrough) ----------------
__global__ void k_pre(const float* __restrict__ x,
                      const float* __restrict__ dwq, const float* __restrict__ dwk, const float* __restrict__ dwv,
                      const float* __restrict__ gq, const float* __restrict__ bq,
                      const float* __restrict__ gk, const float* __restrict__ bk,
                      const float* __restrict__ gv, const float* __restrict__ bv,
                      float* __restrict__ pre) {
    int blk = blockIdx.x;               // which*NIMG + b*TT + t
    int which = blk / NIMG;
    int it = blk - which * NIMG;
    int b = it / TT, t = it - b * TT;
    int c = threadIdx.x;                // 128
    const float* dw = (which == 0) ? dwq : (which == 1) ? dwk : dwv;
    const float* g  = (which == 0) ? gq  : (which == 1) ? gk  : gv;
    const float* bi = (which == 0) ? bq  : (which == 1) ? bk  : bv;
    float val;
    if (t == 0) {
        val = x[(b * TT) * CC + c];
    } else {
        int y = (t - 1) >> 4, xx = (t - 1) & 15;
        float s = 0.f;
        #pragma unroll
        for (int ky = 0; ky < 3; ky++) {
            int yy = y + ky - 1;
            if (yy < 0 || yy > 15) continue;
            #pragma unroll
            for (int kx = 0; kx < 3; kx++) {
                int xb = xx + kx - 1;
                if (xb < 0 || xb > 15) continue;
                s += dw[c * 9 + ky * 3 + kx] * x[(b * TT + 1 + yy * 16 + xb) * CC + c];
            }
        }
        val = s * (g[c] * BN_INV) + bi[c];
    }
    pre[(which * NIMG + it) * CC + c] = val;
}

// ---------------- Kernel A2: QKV projection ----------------
__global__ void k_proj(const float* __restrict__ pre,
                       const float* __restrict__ Wq, const float* __restrict__ Wk, const float* __restrict__ Wv,
                       float* __restrict__ qh, float* __restrict__ kv) {
    int blk = blockIdx.x;
    int which = blk / NIMG;
    int it = blk - which * NIMG;
    int b = it / TT, t = it - b * TT;
    int o = threadIdx.x;                // 128
    __shared__ float row[CC];
    row[o] = pre[(which * NIMG + it) * CC + o];
    __syncthreads();
    const float* W = (which == 0) ? Wq : (which == 1) ? Wk : Wv;
    const float* wr = W + o * CC;
    float acc = 0.f;
    #pragma unroll 8
    for (int c = 0; c < CC; c++) acc += wr[c] * row[c];
    int hh = o >> 4, dd = o & 15;
    long ridx = (long)(b * HH + hh) * TT + t;
    if (which == 0)      qh[ridx * DD + dd] = acc;
    else if (which == 1) kv[ridx * 32 + dd] = acc;
    else                 kv[ridx * 32 + 16 + dd] = acc;
}

// ---------------- Kernel B: score = [first, 0.7*softmax(2r)+0.3*(1-softmax(-2r))] ----------------
__global__ void k_score(const float* __restrict__ asg, float* __restrict__ score) {
    int wid = threadIdx.x >> 6;
    int lane = threadIdx.x & 63;
    int r = blockIdx.x * 4 + wid;
    if (r >= ROWS) return;
    const float* src = asg + (long)r * TT;
    float* dst = score + (long)r * TT;
    float e[4];
    #pragma unroll
    for (int i = 0; i < 4; i++) e[i] = src[1 + lane + 64 * i] * 2.0f;
    float mx = fmaxf(fmaxf(e[0], e[1]), fmaxf(e[2], e[3]));
    mx = wred_max(mx);
    float mn = fminf(fminf(e[0], e[1]), fminf(e[2], e[3]));
    mn = -wred_max(-mn);
    float pe[4], ne[4], ps = 0.f, ns = 0.f;
    #pragma unroll
    for (int i = 0; i < 4; i++) {
        pe[i] = expf(e[i] - mx); ps += pe[i];
        ne[i] = expf(mn - e[i]); ns += ne[i];
    }
    ps = wred_sum(ps); ns = wred_sum(ns);
    float rp = 1.f / ps, rn = 1.f / ns;
    #pragma unroll
    for (int i = 0; i < 4; i++)
        dst[1 + lane + 64 * i] = 0.7f * pe[i] * rp + 0.3f * (1.f - ne[i] * rn);
    if (lane == 0) dst[0] = src[0];
}

// ---------------- Kernel W2: conv_w [o][c2][d] -> wt2 [o][jp][d][v]  (c2 = 32*jp + v) ----------------
__global__ void k_w2(const float* __restrict__ cw, float* __restrict__ wt2) {
    int o = blockIdx.x;     // 256
    int t = threadIdx.x;    // 256
    for (int i = t; i < KTOT; i += 256) {
        int jp = i / 288;
        int r = i - jp * 288;
        int d = r >> 5, v = r & 31;
        wt2[o * KTOT + i] = cw[o * KTOT + (jp * 32 + v) * 9 + d];
    }
}

// ---------------- Kernel C: factorized conv (rank-1 ci = S x KV) ----------------
// Stage 1: P[d][j][o_l][jp] = sum_v W[o][32jp+v][d] * KV[j][v]     (kv hoisted in VGPRs)
// Stage 2: co[o][p] = sum_{d,jp} S[j(p,d)][...jp] * P[d][j][o_l][jp]
__launch_bounds__(256, 2)
__global__ void k_fconv(const float* __restrict__ wt2, const float* __restrict__ score,
                        const float* __restrict__ kv, const float* __restrict__ cb,
                        const float* __restrict__ g2, const float* __restrict__ b2,
                        float* __restrict__ cf) {
    __shared__ float s_S[8][256];          // score rows, cols 1..256 (8 KB)
    __shared__ float s_kv[8][32];          // 1 KB
    __shared__ float s_P[9][8][16][8];     // [d][j][o_l][jp]  36 KB
    int bid = blockIdx.x;
    int oc  = bid / NIMG;                  // o-chunk 0..15
    int img = bid - oc * NIMG;             // b*TT + tp
    int b = img / TT, tp = img - b * TT;
    int tid = threadIdx.x;

    // stage kv rows + score rows (cols 1..256) for this image
    {
        int j = tid >> 5, c = tid & 31;
        int m = tp * 8 + j;
        int hh = m / TT, t = m - hh * TT;
        long row = (long)(b * HH + hh) * TT + t;
        s_kv[j][c] = kv[row * 32 + c];
    }
    #pragma unroll
    for (int it = 0; it < 8; it++) {
        int i = tid + 256 * it;            // 0..2047
        int j = i >> 8, s = i & 255;
        int m = tp * 8 + j;
        int hh = m / TT, t = m - hh * TT;
        long row = (long)(b * HH + hh) * TT + t;
        s_S[j][s] = score[row * TT + 1 + s];
    }
    __syncthreads();

    // ---- stage 1: kv held in registers across the whole d-loop ----
    {
        int o_l = tid >> 4;                // 0..15
        int jp  = tid & 7;                 // 0..7
        int jh  = (tid >> 3) & 1;          // j-half (4 rows each)
        float4 kvr[4][8];
        #pragma unroll
        for (int jj = 0; jj < 4; jj++) {
            const float4* kv4 = (const float4*)(&s_kv[(jh << 2) + jj][0]);
            #pragma unroll
            for (int u = 0; u < 8; u++) kvr[jj][u] = kv4[u];
        }
        const float* gw = wt2 + (((oc << 4) + o_l) * KTOT + jp * 288);
        for (int d = 0; d < 9; d++) {
            const float4* w4 = (const float4*)(gw + (d << 5));
            float4 wv[8];
            #pragma unroll
            for (int u = 0; u < 8; u++) wv[u] = w4[u];
            #pragma unroll
            for (int jj = 0; jj < 4; jj++) {
                float a = 0.f;
                #pragma unroll
                for (int u = 0; u < 8; u++) {
                    a += wv[u].x * kvr[jj][u].x + wv[u].y * kvr[jj][u].y
                       + wv[u].z * kvr[jj][u].z + wv[u].w * kvr[jj][u].w;
                }
                s_P[d][(jh << 2) + jj][o_l][jp] = a;
            }
        }
    }
    __syncthreads();

    // ---- stage 2: thread = (p, og); o set strided by 4 to spread banks ----
    int p  = tid >> 2;                     // 0..63
    int og = tid & 3;                      // o_l = og + io*4
    int yo = p >> 3, xo = p & 7;
    float acc[4] = {0.f, 0.f, 0.f, 0.f};
    for (int dy = 0; dy < 3; dy++) {
        int y = 2 * yo - 1 + dy;
        if (y < 0) continue;               // top pad; y<=15 always
        int j = y >> 1, ypar = y & 1;
        #pragma unroll
        for (int dx = 0; dx < 3; dx++) {
            int x = 2 * xo - 1 + dx;
            if (x < 0) continue;           // left pad; x<=15 always
            int d = dy * 3 + dx;
            const float4* sp4 = (const float4*)(&s_S[j][(ypar * 16 + x) << 3]);
            float4 s0 = sp4[0], s1 = sp4[1];
            #pragma unroll
            for (int io = 0; io < 4; io++) {
                const float4* pp = (const float4*)(&s_P[d][j][og + (io << 2)][0]);
                float4 p0 = pp[0], p1 = pp[1];
                acc[io] += s0.x * p0.x + s0.y * p0.y + s0.z * p0.z + s0.w * p0.w
                         + s1.x * p1.x + s1.y * p1.y + s1.z * p1.z + s1.w * p1.w;
            }
        }
    }

    // epilogue: bias + BN -> cf layout (B,H,T,64,32)
    int pcf_hi = p >> 5, cp = p & 31;
    #pragma unroll
    for (int io = 0; io < 4; io++) {
        int o = (oc << 4) + og + (io << 2);
        int hh_o = o >> 5, c = o & 31;
        long rowcf = (long)(b * HH + hh_o) * TT + tp;
        int pcf = 2 * c + pcf_hi;
        cf[(rowcf * 64 + pcf) * 32 + cp] = (acc[io] + cb[o]) * (g2[o] * BN_INV) + b2[o];
    }
}

// ---------------- Kernel D: 65-key attention + GELU ----------------
__global__ void k_attn(const float* __restrict__ qh, const float* __restrict__ kv,
                       const float* __restrict__ score, const float* __restrict__ cf,
                       float* __restrict__ out) {
    int row = blockIdx.x;               // (b*8+hh)*257+t
    int lane = threadIdx.x;             // 64
    int b = row / (HH * TT);
    int rem = row - b * (HH * TT);
    int hh = rem / TT, t = rem - hh * TT;
    __shared__ float q[16];
    __shared__ float pv[66];
    __shared__ float vv[65][16];
    if (lane < 16) q[lane] = qh[(long)row * DD + lane];
    __syncthreads();
    const float SCALE = 0.08838834764831845f;
    float d, d2 = -INFINITY;
    if (lane == 0) {
        float s0 = score[(long)row * TT];
        float a = 0.f;
        #pragma unroll
        for (int i = 0; i < 16; i++) {
            float kk = s0 * kv[(long)row * 32 + i];
            a += q[i] * kk;
            vv[0][i] = s0 * kv[(long)row * 32 + 16 + i];
        }
        d = a * SCALE;
        const float* b63 = cf + ((long)row * 64 + 63) * 32;
        a = 0.f;
        #pragma unroll
        for (int i = 0; i < 16; i++) { a += q[i] * b63[i]; vv[64][i] = b63[16 + i]; }
        d2 = a * SCALE;
    } else {
        const float* bp = cf + ((long)row * 64 + (lane - 1)) * 32;
        float a = 0.f;
        #pragma unroll
        for (int i = 0; i < 16; i++) { a += q[i] * bp[i]; vv[lane][i] = bp[16 + i]; }
        d = a * SCALE;
    }
    float mx = wred_max(fmaxf(d, d2));
    float p = expf(d - mx);
    float p2 = (lane == 0) ? expf(d2 - mx) : 0.f;
    float sum = wred_sum(p + p2);
    pv[lane] = p;
    if (lane == 0) pv[64] = p2;
    __syncthreads();
    if (lane < 16) {
        float a = 0.f;
        for (int j = 0; j < 65; j++) a += pv[j] * vv[j][lane];
        float o = a / sum;
        float g = 0.5f * o * (1.f + erff(o * 0.70710678118654752f));
        out[(long)(b * TT + t) * CC + hh * DD + lane] = g;
    }
}

extern "C" void kernel_launch(void* const* d_in, const int* in_sizes, int n_in,
                              void* d_out, int out_size, void* d_ws, size_t ws_size,
                              hipStream_t stream) {
    const float* x   = (const float*)d_in[0];
    const float* asg = (const float*)d_in[1];
    const float* dwq = (const float*)d_in[2];
    const float* dwk = (const float*)d_in[3];
    const float* dwv = (const float*)d_in[4];
    const float* gq  = (const float*)d_in[5];
    const float* bq  = (const float*)d_in[6];
    const float* gk  = (const float*)d_in[7];
    const float* bk  = (const float*)d_in[8];
    const float* gv  = (const float*)d_in[9];
    const float* bv  = (const float*)d_in[10];
    const float* Wq  = (const float*)d_in[11];
    const float* Wk  = (const float*)d_in[12];
    const float* Wv  = (const float*)d_in[13];
    const float* cw  = (const float*)d_in[14];
    const float* cb  = (const float*)d_in[15];
    const float* g2  = (const float*)d_in[16];
    const float* b2  = (const float*)d_in[17];
    float* out = (float*)d_out;

    float* ws = (float*)d_ws;
    float* qh    = ws;                    // 65792
    float* kvv   = qh + 65792;            // 131584
    float* score = kvv + 131584;          // 1056784
    float* wt2   = score + 1056784;       // 589824
    float* cf    = wt2 + 589824;          // 8421376
    float* pre   = cf + 8421376;          // 197376   (total ~41.9 MB)

    k_pre<<<3 * NIMG, CC, 0, stream>>>(x, dwq, dwk, dwv, gq, bq, gk, bk, gv, bv, pre);
    k_proj<<<3 * NIMG, CC, 0, stream>>>(pre, Wq, Wk, Wv, qh, kvv);
    k_score<<<ROWS / 4, 256, 0, stream>>>(asg, score);
    k_w2<<<C2O, 256, 0, stream>>>(cw, wt2);
    k_fconv<<<16 * NIMG, 256, 0, stream>>>(wt2, score, kvv, cb, g2, b2, cf);
    k_attn<<<ROWS, 64, 0, stream>>>(qh, kvv, score, cf, out);
}

// Round 8
// 342.362 us; speedup vs baseline: 2.5788x; 1.2004x over previous
//
#include <hip/hip_runtime.h>

#define BB 2
#define TT 257
#define CC 128
#define HH 8
#define DD 16
#define C2O 256
#define NIMG (BB*TT)      // 514
#define ROWS (BB*HH*TT)   // 4112
#define KTOT 2304

static __device__ __forceinline__ float wred_max(float v) {
    #pragma unroll
    for (int off = 32; off; off >>= 1) v = fmaxf(v, __shfl_xor(v, off, 64));
    return v;
}
static __device__ __forceinline__ float wred_sum(float v) {
    #pragma unroll
    for (int off = 32; off; off >>= 1) v += __shfl_xor(v, off, 64);
    return v;
}

#define BN_INV 0.9999950000374997f

// ---------------- Kernel A1: depthwise 3x3 + BN (+cls passthrough) ----------------
__global__ void k_pre(const float* __restrict__ x,
                      const float* __restrict__ dwq, const float* __restrict__ dwk, const float* __restrict__ dwv,
                      const float* __restrict__ gq, const float* __restrict__ bq,
                      const float* __restrict__ gk, const float* __restrict__ bk,
                      const float* __restrict__ gv, const float* __restrict__ bv,
                      float* __restrict__ pre) {
    int blk = blockIdx.x;               // which*NIMG + b*TT + t
    int which = blk / NIMG;
    int it = blk - which * NIMG;
    int b = it / TT, t = it - b * TT;
    int c = threadIdx.x;                // 128
    const float* dw = (which == 0) ? dwq : (which == 1) ? dwk : dwv;
    const float* g  = (which == 0) ? gq  : (which == 1) ? gk  : gv;
    const float* bi = (which == 0) ? bq  : (which == 1) ? bk  : bv;
    float val;
    if (t == 0) {
        val = x[(b * TT) * CC + c];
    } else {
        int y = (t - 1) >> 4, xx = (t - 1) & 15;
        float s = 0.f;
        #pragma unroll
        for (int ky = 0; ky < 3; ky++) {
            int yy = y + ky - 1;
            if (yy < 0 || yy > 15) continue;
            #pragma unroll
            for (int kx = 0; kx < 3; kx++) {
                int xb = xx + kx - 1;
                if (xb < 0 || xb > 15) continue;
                s += dw[c * 9 + ky * 3 + kx] * x[(b * TT + 1 + yy * 16 + xb) * CC + c];
            }
        }
        val = s * (g[c] * BN_INV) + bi[c];
    }
    pre[(which * NIMG + it) * CC + c] = val;
}

// ---------------- Kernel A2: QKV projection ----------------
__global__ void k_proj(const float* __restrict__ pre,
                       const float* __restrict__ Wq, const float* __restrict__ Wk, const float* __restrict__ Wv,
                       float* __restrict__ qh, float* __restrict__ kv) {
    int blk = blockIdx.x;
    int which = blk / NIMG;
    int it = blk - which * NIMG;
    int b = it / TT, t = it - b * TT;
    int o = threadIdx.x;                // 128
    __shared__ float row[CC];
    row[o] = pre[(which * NIMG + it) * CC + o];
    __syncthreads();
    const float* W = (which == 0) ? Wq : (which == 1) ? Wk : Wv;
    const float* wr = W + o * CC;
    float acc = 0.f;
    #pragma unroll 8
    for (int c = 0; c < CC; c++) acc += wr[c] * row[c];
    int hh = o >> 4, dd = o & 15;
    long ridx = (long)(b * HH + hh) * TT + t;
    if (which == 0)      qh[ridx * DD + dd] = acc;
    else if (which == 1) kv[ridx * 32 + dd] = acc;
    else                 kv[ridx * 32 + 16 + dd] = acc;
}

// ---------------- Kernel B: score = [first, 0.7*softmax(2r)+0.3*(1-softmax(-2r))] ----------------
__global__ void k_score(const float* __restrict__ asg, float* __restrict__ score) {
    int wid = threadIdx.x >> 6;
    int lane = threadIdx.x & 63;
    int r = blockIdx.x * 4 + wid;
    if (r >= ROWS) return;
    const float* src = asg + (long)r * TT;
    float* dst = score + (long)r * TT;
    float e[4];
    #pragma unroll
    for (int i = 0; i < 4; i++) e[i] = src[1 + lane + 64 * i] * 2.0f;
    float mx = fmaxf(fmaxf(e[0], e[1]), fmaxf(e[2], e[3]));
    mx = wred_max(mx);
    float mn = fminf(fminf(e[0], e[1]), fminf(e[2], e[3]));
    mn = -wred_max(-mn);
    float pe[4], ne[4], ps = 0.f, ns = 0.f;
    #pragma unroll
    for (int i = 0; i < 4; i++) {
        pe[i] = expf(e[i] - mx); ps += pe[i];
        ne[i] = expf(mn - e[i]); ns += ne[i];
    }
    ps = wred_sum(ps); ns = wred_sum(ns);
    float rp = 1.f / ps, rn = 1.f / ns;
    #pragma unroll
    for (int i = 0; i < 4; i++)
        dst[1 + lane + 64 * i] = 0.7f * pe[i] * rp + 0.3f * (1.f - ne[i] * rn);
    if (lane == 0) dst[0] = src[0];
}

// ---------------- Kernel W2: conv_w [o][c2][d] -> wt2 [o][jp][d][v]  (c2 = 32*jp + v) ----------------
__global__ void k_w2(const float* __restrict__ cw, float* __restrict__ wt2) {
    int o = blockIdx.x;     // 256
    int t = threadIdx.x;    // 256
    for (int i = t; i < KTOT; i += 256) {
        int jp = i / 288;
        int r = i - jp * 288;
        int d = r >> 5, v = r & 31;
        wt2[o * KTOT + i] = cw[o * KTOT + (jp * 32 + v) * 9 + d];
    }
}

// ---------------- Kernel C: factorized conv, v-quarter threads + DPP reduce ----------------
// Stage 1: thread (o_l,jpp,jq) computes partial P over its v-quarter for all 8 j and
//          2 jp's; quad shfl_xor combines; result in s_P[dx][j][o_l*8+jp] (dy-chunked).
// Stage 2: co[o][p] = sum_{dx,jp} S[j(p,dy)][...] * P[dx][j][o_l*8+jp]
__launch_bounds__(256, 4)
__global__ void k_fconv(const float* __restrict__ wt2, const float* __restrict__ score,
                        const float* __restrict__ kv, const float* __restrict__ cb,
                        const float* __restrict__ g2, const float* __restrict__ b2,
                        float* __restrict__ cf) {
    __shared__ float s_S[8][260];          // 8.3 KB (pad 260: j-rows shifted 4 banks)
    __shared__ float s_kv[8][32];          // 1 KB
    __shared__ float s_P[3][8][132];       // 12.7 KB  [dx][j][o_l*8+jp], j-stride 132
    int bid = blockIdx.x;
    int oc  = bid / NIMG;                  // o-chunk 0..15
    int img = bid - oc * NIMG;             // b*TT + tp
    int b = img / TT, tp = img - b * TT;
    int tid = threadIdx.x;

    // stage kv rows + score rows (cols 1..256) for this image
    {
        int j = tid >> 5, c = tid & 31;
        int m = tp * 8 + j;
        int hh = m / TT, t = m - hh * TT;
        long row = (long)(b * HH + hh) * TT + t;
        s_kv[j][c] = kv[row * 32 + c];
    }
    #pragma unroll
    for (int it = 0; it < 8; it++) {
        int i = tid + 256 * it;            // 0..2047
        int j = i >> 8, s = i & 255;
        int m = tp * 8 + j;
        int hh = m / TT, t = m - hh * TT;
        long row = (long)(b * HH + hh) * TT + t;
        s_S[j][s] = score[row * TT + 1 + s];
    }
    __syncthreads();

    // stage-1 decomposition
    int o_l = tid >> 4;                    // 0..15
    int jpp = (tid >> 2) & 3;              // 0..3 (jp pair)
    int jq  = tid & 3;                     // v-quarter
    // stage-2 decomposition
    int p  = tid >> 2;                     // 0..63
    int og = tid & 3;                      // o_l = og + io*4
    int yo = p >> 3, xo = p & 7;

    // kv quarter for all 8 j: 64 floats, guaranteed register-resident
    float4 kr[8][2];
    #pragma unroll
    for (int j = 0; j < 8; j++) {
        const float4* p4 = (const float4*)(&s_kv[j][jq << 3]);
        kr[j][0] = p4[0]; kr[j][1] = p4[1];
    }

    const float* gw = wt2 + (long)((oc << 4) + o_l) * KTOT + (jpp << 1) * 288 + (jq << 3);
    float acc[4] = {0.f, 0.f, 0.f, 0.f};

    for (int dy = 0; dy < 3; dy++) {
        // ---- stage 1 for d = dy*3 + dx ----
        #pragma unroll
        for (int dx = 0; dx < 3; dx++) {
            int d = dy * 3 + dx;
            #pragma unroll
            for (int jpl = 0; jpl < 2; jpl++) {
                const float4* w4 = (const float4*)(gw + jpl * 288 + (d << 5));
                float4 wa = w4[0], wb = w4[1];
                float part[8];
                #pragma unroll
                for (int j = 0; j < 8; j++) {
                    float4 k0 = kr[j][0], k1 = kr[j][1];
                    part[j] = wa.x*k0.x + wa.y*k0.y + wa.z*k0.z + wa.w*k0.w
                            + wb.x*k1.x + wb.y*k1.y + wb.z*k1.z + wb.w*k1.w;
                }
                #pragma unroll
                for (int j = 0; j < 8; j++) {
                    part[j] += __shfl_xor(part[j], 1, 64);   // quad-perm DPP
                    part[j] += __shfl_xor(part[j], 2, 64);
                }
                // lane jq owns j = 2*jq, 2*jq+1 (static-index selects, rule #20)
                #pragma unroll
                for (int i = 0; i < 2; i++) {
                    float v = (jq == 0) ? part[i] : (jq == 1) ? part[2 + i]
                            : (jq == 2) ? part[4 + i] : part[6 + i];
                    int j = (jq << 1) + i;
                    s_P[dx][j][(o_l << 3) + (jpp << 1) + jpl] = v;
                }
            }
        }
        __syncthreads();
        // ---- stage 2 for this dy ----
        int y = 2 * yo - 1 + dy;
        if (y >= 0) {                      // y<=15 always
            int j = y >> 1, ypar = y & 1;
            #pragma unroll
            for (int dx = 0; dx < 3; dx++) {
                int x = 2 * xo - 1 + dx;
                if (x < 0) continue;       // x<=15 always
                const float4* sp4 = (const float4*)(&s_S[j][((ypar << 4) + x) << 3]);
                float4 s0 = sp4[0], s1 = sp4[1];
                #pragma unroll
                for (int io = 0; io < 4; io++) {
                    const float4* pp = (const float4*)(&s_P[dx][j][(og + (io << 2)) << 3]);
                    float4 p0 = pp[0], p1 = pp[1];
                    acc[io] += s0.x * p0.x + s0.y * p0.y + s0.z * p0.z + s0.w * p0.w
                             + s1.x * p1.x + s1.y * p1.y + s1.z * p1.z + s1.w * p1.w;
                }
            }
        }
        __syncthreads();
    }

    // epilogue: bias + BN -> cf layout (B,H,T,64,32)
    int pcf_hi = p >> 5, cp = p & 31;
    #pragma unroll
    for (int io = 0; io < 4; io++) {
        int o = (oc << 4) + og + (io << 2);
        int hh_o = o >> 5, c = o & 31;
        long rowcf = (long)(b * HH + hh_o) * TT + tp;
        int pcf = 2 * c + pcf_hi;
        cf[(rowcf * 64 + pcf) * 32 + cp] = (acc[io] + cb[o]) * (g2[o] * BN_INV) + b2[o];
    }
}

// ---------------- Kernel D: 65-key attention + GELU ----------------
__global__ void k_attn(const float* __restrict__ qh, const float* __restrict__ kv,
                       const float* __restrict__ score, const float* __restrict__ cf,
                       float* __restrict__ out) {
    int row = blockIdx.x;               // (b*8+hh)*257+t
    int lane = threadIdx.x;             // 64
    int b = row / (HH * TT);
    int rem = row - b * (HH * TT);
    int hh = rem / TT, t = rem - hh * TT;
    __shared__ float q[16];
    __shared__ float pv[66];
    __shared__ float vv[65][16];
    if (lane < 16) q[lane] = qh[(long)row * DD + lane];
    __syncthreads();
    const float SCALE = 0.08838834764831845f;
    float d, d2 = -INFINITY;
    if (lane == 0) {
        float s0 = score[(long)row * TT];
        float a = 0.f;
        #pragma unroll
        for (int i = 0; i < 16; i++) {
            float kk = s0 * kv[(long)row * 32 + i];
            a += q[i] * kk;
            vv[0][i] = s0 * kv[(long)row * 32 + 16 + i];
        }
        d = a * SCALE;
        const float* b63 = cf + ((long)row * 64 + 63) * 32;
        a = 0.f;
        #pragma unroll
        for (int i = 0; i < 16; i++) { a += q[i] * b63[i]; vv[64][i] = b63[16 + i]; }
        d2 = a * SCALE;
    } else {
        const float* bp = cf + ((long)row * 64 + (lane - 1)) * 32;
        float a = 0.f;
        #pragma unroll
        for (int i = 0; i < 16; i++) { a += q[i] * bp[i]; vv[lane][i] = bp[16 + i]; }
        d = a * SCALE;
    }
    float mx = wred_max(fmaxf(d, d2));
    float p = expf(d - mx);
    float p2 = (lane == 0) ? expf(d2 - mx) : 0.f;
    float sum = wred_sum(p + p2);
    pv[lane] = p;
    if (lane == 0) pv[64] = p2;
    __syncthreads();
    if (lane < 16) {
        float a = 0.f;
        for (int j = 0; j < 65; j++) a += pv[j] * vv[j][lane];
        float o = a / sum;
        float g = 0.5f * o * (1.f + erff(o * 0.70710678118654752f));
        out[(long)(b * TT + t) * CC + hh * DD + lane] = g;
    }
}

extern "C" void kernel_launch(void* const* d_in, const int* in_sizes, int n_in,
                              void* d_out, int out_size, void* d_ws, size_t ws_size,
                              hipStream_t stream) {
    const float* x   = (const float*)d_in[0];
    const float* asg = (const float*)d_in[1];
    const float* dwq = (const float*)d_in[2];
    const float* dwk = (const float*)d_in[3];
    const float* dwv = (const float*)d_in[4];
    const float* gq  = (const float*)d_in[5];
    const float* bq  = (const float*)d_in[6];
    const float* gk  = (const float*)d_in[7];
    const float* bk  = (const float*)d_in[8];
    const float* gv  = (const float*)d_in[9];
    const float* bv  = (const float*)d_in[10];
    const float* Wq  = (const float*)d_in[11];
    const float* Wk  = (const float*)d_in[12];
    const float* Wv  = (const float*)d_in[13];
    const float* cw  = (const float*)d_in[14];
    const float* cb  = (const float*)d_in[15];
    const float* g2  = (const float*)d_in[16];
    const float* b2  = (const float*)d_in[17];
    float* out = (float*)d_out;

    float* ws = (float*)d_ws;
    float* qh    = ws;                    // 65792
    float* kvv   = qh + 65792;            // 131584
    float* score = kvv + 131584;          // 1056784
    float* wt2   = score + 1056784;       // 589824
    float* cf    = wt2 + 589824;          // 8421376
    float* pre   = cf + 8421376;          // 197376   (total ~41.9 MB)

    k_pre<<<3 * NIMG, CC, 0, stream>>>(x, dwq, dwk, dwv, gq, bq, gk, bk, gv, bv, pre);
    k_proj<<<3 * NIMG, CC, 0, stream>>>(pre, Wq, Wk, Wv, qh, kvv);
    k_score<<<ROWS / 4, 256, 0, stream>>>(asg, score);
    k_w2<<<C2O, 256, 0, stream>>>(cw, wt2);
    k_fconv<<<16 * NIMG, 256, 0, stream>>>(wt2, score, kvv, cb, g2, b2, cf);
    k_attn<<<ROWS, 64, 0, stream>>>(qh, kvv, score, cf, out);
}